// Round 8
// baseline (3070.300 us; speedup 1.0000x reference)
//
#include <hip/hip_runtime.h>
#include <hip/hip_bf16.h>
#include <stdint.h>

// Persistent LSTM v2: 16 groups (16 batches) x 16 WGs (32 hids) x 4 waves
// (8 hids each, FULL K=512 per wave -> no K-merge, no __syncthreads in loop).
// Weights register-resident. Per-step h exchange via d_ws bf16 double buffer,
// agent-scope atomics; per-WAVE signal after own-store vmcnt drain.
// Counter target = 64 waves per group per step.

#define NB 256
#define NT 512
#define NF 130
#define NK 128
#define NH 512

typedef float f32x4 __attribute__((ext_vector_type(4)));
typedef float f32x2 __attribute__((ext_vector_type(2)));
typedef short bf16x8 __attribute__((ext_vector_type(8)));

__device__ __forceinline__ short bf1(float f) {
  union { float f; uint32_t u; } v; v.f = f;
  uint32_t r = (v.u + 0x7FFFu + ((v.u >> 16) & 1u)) >> 16;  // RNE
  return (short)r;
}

__device__ __forceinline__ bf16x8 cvt8(const float* p) {
  bf16x8 r;
#pragma unroll
  for (int i = 0; i < 4; ++i) {
    f32x2 t = *(const f32x2*)(p + 2 * i);   // 8B-aligned at every call site
    r[2 * i]     = bf1(t[0]);
    r[2 * i + 1] = bf1(t[1]);
  }
  return r;
}

__device__ __forceinline__ float fsig(float x) {
  return __builtin_amdgcn_rcpf(1.0f + __builtin_amdgcn_exp2f(-1.44269504f * x));
}
__device__ __forceinline__ float ftanh(float x) {
  return 2.0f * __builtin_amdgcn_rcpf(1.0f + __builtin_amdgcn_exp2f(-2.88539008f * x)) - 1.0f;
}

__global__ __launch_bounds__(256, 1) void lstm_pers(
    const float* __restrict__ xin, const int* __restrict__ lens,
    const float* __restrict__ h0, const float* __restrict__ c0,
    const float* __restrict__ Wih, const float* __restrict__ Whh,
    const float* __restrict__ bih, const float* __restrict__ bhh,
    float* __restrict__ out, unsigned* __restrict__ cnt,
    unsigned short* __restrict__ hbuf /* [2][NB][NH] bf16 bits */) {
  const int blk = blockIdx.x;
  const int g  = blk & 15;   // batch group; blk%8 constant within group -> XCD-affine
  const int s  = blk >> 4;   // hidden slice 0..15 (32 hids)
  const int tid = threadIdx.x;
  const int w  = tid >> 6;   // wave 0..3: hids [hbase, hbase+8)
  const int l  = tid & 63;
  const int q  = l >> 4;
  const int col = l & 15;
  const int bidx = (g << 4) + col;       // lane's batch (B/C col)
  const int qh = (l & 15) >> 2;          // A-frag row = 4*qh + sg
  const int sg = l & 3;                  // gate index (i,f,g,o)
  const int hbase = (s << 5) + (w << 3); // wave's hidden base

  // ---- weights -> registers, once. No duplication across waves. ----
  bf16x8 whh[2][16];  // [m-tile][kt], k = kt*32 + q*8 + j  (full K=512)
  bf16x8 wih[2][4];   // [m-tile][kt], feat = kt*32 + q*8 + j (K=128)
#pragma unroll
  for (int m = 0; m < 2; ++m) {
    const int grow = sg * NH + hbase + (m << 2) + qh;  // global gate row
    const float* pw = Whh + (size_t)grow * NH + q * 8;
#pragma unroll
    for (int kt = 0; kt < 16; ++kt) whh[m][kt] = cvt8(pw + kt * 32);
    const float* pi = Wih + (size_t)grow * NK + q * 8;
#pragma unroll
    for (int kt = 0; kt < 4; ++kt) wih[m][kt] = cvt8(pi + kt * 32);
  }

  f32x4 bias[2];
  float cst[2];
  const int blen = lens[bidx];
#pragma unroll
  for (int m = 0; m < 2; ++m) {
    const int hid = hbase + (m << 2) + q;
#pragma unroll
    for (int p = 0; p < 4; ++p)
      bias[m][p] = bih[p * NH + hid] + bhh[p * NH + hid];
    cst[m] = c0[(size_t)bidx * NH + hid];
    __hip_atomic_store(&hbuf[(size_t)bidx * NH + hid],
                       (unsigned short)bf1(h0[(size_t)bidx * NH + hid]),
                       __ATOMIC_RELAXED, __HIP_MEMORY_SCOPE_AGENT);
  }

  // release h0: drain own stores (they are sc1 -> complete at LLC), then signal
  asm volatile("s_waitcnt vmcnt(0)" ::: "memory");
  if (l == 0)
    __hip_atomic_fetch_add(cnt + g * 32, 1u, __ATOMIC_RELAXED, __HIP_MEMORY_SCOPE_AGENT);

  // x prefetch for t=0 (raw f32, carried in regs across the sync window)
  f32x2 xr[16];
  {
    const float* px = xin + (size_t)bidx * (NT * NF) + q * 8;
#pragma unroll
    for (int kt = 0; kt < 4; ++kt)
#pragma unroll
      for (int i = 0; i < 4; ++i)
        xr[kt * 4 + i] = *(const f32x2*)(px + kt * 32 + i * 2);
  }

  const unsigned short* hsb = hbuf + (size_t)bidx * NH + q * 8;
  unsigned short* hwb = hbuf + (size_t)bidx * NH;
  int dead = 0;

  for (int t = 0; t < NT; ++t) {
    // ---- x-projection from prefetched regs (acc seeded with bias) ----
    f32x4 acc[2];
    acc[0] = bias[0];
    acc[1] = bias[1];
#pragma unroll
    for (int kt = 0; kt < 4; ++kt) {
      bf16x8 xf;
#pragma unroll
      for (int i = 0; i < 4; ++i) {
        xf[2 * i]     = bf1(xr[kt * 4 + i][0]);
        xf[2 * i + 1] = bf1(xr[kt * 4 + i][1]);
      }
#pragma unroll
      for (int m = 0; m < 2; ++m)
        acc[m] = __builtin_amdgcn_mfma_f32_16x16x32_bf16(wih[m][kt], xf, acc[m], 0, 0, 0);
    }
    // ---- per-wave wait: all 64 waves of this group published h(t) ----
    if (l == 0 && !dead) {
      const unsigned tgt = 64u * (unsigned)(t + 1);
      long spins = 0;
      while (__hip_atomic_load(cnt + g * 32, __ATOMIC_RELAXED, __HIP_MEMORY_SCOPE_AGENT) < tgt) {
        __builtin_amdgcn_s_sleep(1);
        if (++spins > (1L << 19)) { dead = 1; break; }  // bail, don't hang
      }
    }
    asm volatile("" ::: "memory");  // keep h loads below the spin
    // ---- h loads: ALL issued up front (latency pipelines), then MFMA ----
    const unsigned short* hs = hsb + ((size_t)(t & 1)) * (NB * NH);
    union U { unsigned long long u[2]; bf16x8 v; };
    U hu[16];
#pragma unroll
    for (int kt = 0; kt < 16; ++kt) {
      hu[kt].u[0] = __hip_atomic_load((const unsigned long long*)(hs + kt * 32),
                                      __ATOMIC_RELAXED, __HIP_MEMORY_SCOPE_AGENT);
      hu[kt].u[1] = __hip_atomic_load((const unsigned long long*)(hs + kt * 32 + 4),
                                      __ATOMIC_RELAXED, __HIP_MEMORY_SCOPE_AGENT);
    }
#pragma unroll
    for (int kt = 0; kt < 16; ++kt)
#pragma unroll
      for (int m = 0; m < 2; ++m)
        acc[m] = __builtin_amdgcn_mfma_f32_16x16x32_bf16(whh[m][kt], hu[kt].v, acc[m], 0, 0, 0);
    // ---- nonlinearity + h/out store (each wave owns its 8 hids) ----
    unsigned short* hw = hwb + ((size_t)((t + 1) & 1)) * (NB * NH);
#pragma unroll
    for (int m = 0; m < 2; ++m) {
      const int hid = hbase + (m << 2) + q;
      float ig = fsig(acc[m][0]);
      float fg = fsig(acc[m][1]);
      float gg = ftanh(acc[m][2]);
      float og = fsig(acc[m][3]);
      float cc = fg * cst[m] + ig * gg;
      cst[m] = cc;
      float hh = og * ftanh(cc);
      __hip_atomic_store(&hw[hid], (unsigned short)bf1(hh),
                         __ATOMIC_RELAXED, __HIP_MEMORY_SCOPE_AGENT);
      if (t == blen - 1) out[(size_t)bidx * NH + hid] = hh;
    }
    // release: drain own stores only (no barrier, no fence), then signal
    asm volatile("s_waitcnt vmcnt(0)" ::: "memory");
    if (l == 0)
      __hip_atomic_fetch_add(cnt + g * 32, 1u, __ATOMIC_RELAXED, __HIP_MEMORY_SCOPE_AGENT);
    // x prefetch for t+1 overlaps counter propagation + peer latency
    if (t + 1 < NT) {
      const float* px = xin + (size_t)bidx * (NT * NF) + (size_t)(t + 1) * NF + q * 8;
#pragma unroll
      for (int kt = 0; kt < 4; ++kt)
#pragma unroll
        for (int i = 0; i < 4; ++i)
          xr[kt * 4 + i] = *(const f32x2*)(px + kt * 32 + i * 2);
    }
  }
}

extern "C" void kernel_launch(void* const* d_in, const int* in_sizes, int n_in,
                              void* d_out, int out_size, void* d_ws, size_t ws_size,
                              hipStream_t stream) {
  const float* xin  = (const float*)d_in[0];
  const int*   lens = (const int*)d_in[1];
  const float* h0   = (const float*)d_in[2];
  const float* c0   = (const float*)d_in[3];
  const float* Wih  = (const float*)d_in[4];
  const float* Whh  = (const float*)d_in[5];
  const float* bih  = (const float*)d_in[6];
  const float* bhh  = (const float*)d_in[7];
  float* out = (float*)d_out;

  unsigned* cnt = (unsigned*)d_ws;                              // 16 counters, 128B apart
  unsigned short* hbuf = (unsigned short*)((char*)d_ws + 4096); // 2*256*512 bf16 = 512KB

  hipMemsetAsync(d_ws, 0, 4096, stream);  // zero counters (ws is re-poisoned)
  lstm_pers<<<dim3(256), dim3(256), 0, stream>>>(xin, lens, h0, c0, Wih, Whh, bih, bhh,
                                                 out, cnt, hbuf);
}